// Round 3
// baseline (372.367 us; speedup 1.0000x reference)
//
#include <hip/hip_runtime.h>

// Multi-head attention, B=4 S=2048 D=768 H=8 DH=96. FP32 I/O, f16 MFMA compute.
// R11: attn KV-split=2: grid (8,32,2), 512thr / 8 waves x 32 q-rows; each block
//      does half the KV tiles and writes normalized f32 partials + (m,l);
//      combine_kernel merges (f32 math, no extra f16 rounding). 16 waves/CU
//      (vs R2's 8) with R2's low LDS-traffic structure. Runtime ws guard
//      (needs 68.7MB) with exact-R1 attn as fallback.
// Buffers: ws = [WqT|WkT|WvT|WoT | Q16 | Xk16 | Xv16 | Xq16] = 55.05MB
//          + during attn: Op0 f32 overlays Xk16+Xv16 (25.2MB, dead),
//            Op1 f32 at Xq16 (extends 12.6MB past), ML 1MB -> need 68.7MB.
//          d_out = [VT | K16] f16 until GEMM_O overwrites (fp32)
//          A16 -> Xq buffer (dead after QKV GEMM; harness restores d_in).

typedef unsigned short u16;
typedef _Float16 h16;
typedef h16 h16x8 __attribute__((ext_vector_type(8)));
typedef __fp16 fp16x2 __attribute__((ext_vector_type(2)));
typedef __fp16 fp16x4 __attribute__((ext_vector_type(4)));
typedef unsigned short u16x8 __attribute__((ext_vector_type(8)));
typedef unsigned short u16x4 __attribute__((ext_vector_type(4)));
typedef float f32x4 __attribute__((ext_vector_type(4)));

__device__ __forceinline__ u16 f2h(float f) {
  union { h16 h; u16 u; } c; c.h = (h16)f; return c.u;
}

__device__ __forceinline__ void gll16(const void* g, void* l) {
  __builtin_amdgcn_global_load_lds(
      (const __attribute__((address_space(1))) void*)g,
      (__attribute__((address_space(3))) void*)l, 16, 0, 0);
}

// ---------------------------------------------------------------------------
// prep: WqT/WkT/WvT [n=h*96+kk][d] from W[h][d][kk]; WoT [n][k] from Wo[k][n];
//       plus Xk16/Xv16[/Xq16] = f16(X) conversions (gll16 staging in gemm_qkv)
// ---------------------------------------------------------------------------
__global__ __launch_bounds__(256) void prep_kernel(
    const float* __restrict__ Wq, const float* __restrict__ Wk,
    const float* __restrict__ Wv, const float* __restrict__ Wo,
    const float* __restrict__ Xk, const float* __restrict__ Xv,
    const float* __restrict__ Xq,
    u16* __restrict__ WqT, u16* __restrict__ WkT,
    u16* __restrict__ WvT, u16* __restrict__ WoT,
    u16* __restrict__ Xk16, u16* __restrict__ Xv16, u16* __restrict__ Xq16)
{
  const long gid = (long)blockIdx.x * 256 + threadIdx.x;
  if (gid >= 294912) {
    long i = gid - 294912;                 // 0 .. nx*786432-1
    const int t = (int)(i / 786432);       // 0: Xk  1: Xv  2: Xq
    const long e = (i % 786432) * 8;
    const float* src = (t == 0) ? Xk : (t == 1) ? Xv : Xq;
    u16* dst = (t == 0) ? Xk16 : (t == 1) ? Xv16 : Xq16;
    f32x4 a = *(const f32x4*)(&src[e]);
    f32x4 b = *(const f32x4*)(&src[e + 4]);
    u16x8 v;
    #pragma unroll
    for (int j = 0; j < 4; j++) { v[j] = f2h(a[j]); v[4 + j] = f2h(b[j]); }
    *(u16x8*)(&dst[e]) = v;
    return;
  }
  int idx = (int)gid * 8;
  int region = idx / 589824;
  int i = idx % 589824;
  int n = i / 768;
  int d = i % 768;
  u16x8 v;
  if (region == 3) {
    #pragma unroll
    for (int j = 0; j < 8; j++) v[j] = f2h(Wo[(size_t)(d + j) * 768 + n]);
    *(u16x8*)(&WoT[i]) = v;
  } else {
    int h = n / 96, kk = n % 96;
    const float* W = (region == 0) ? Wq : (region == 1) ? Wk : Wv;
    u16* T = (region == 0) ? WqT : (region == 1) ? WkT : WvT;
    #pragma unroll
    for (int j = 0; j < 8; j++) v[j] = f2h(W[(size_t)h * 73728 + (size_t)(d + j) * 96 + kk]);
    *(u16x8*)(&T[i]) = v;
  }
}

// ---------------------------------------------------------------------------
// Batched QKV GEMM. qfp32=0: all z use f16 A via global_load_lds (m97 path).
// qfp32=1: z=0 falls back to fp32 A staged with in-register cvt.
// ---------------------------------------------------------------------------
#define GK 768

__global__ __launch_bounds__(256) void gemm_qkv(
    const float* __restrict__ XqF, const u16* __restrict__ Xq16,
    const u16* __restrict__ Xk16, const u16* __restrict__ Xv16,
    const u16* __restrict__ WT,
    const float* __restrict__ bq, const float* __restrict__ bk,
    const float* __restrict__ bv,
    u16* __restrict__ Q16, u16* __restrict__ K16, u16* __restrict__ VT,
    int qfp32)
{
  const int z = blockIdx.z;
  const u16* BT = WT + (size_t)z * 589824;
  const float* bias = (z == 0) ? bq : (z == 1) ? bk : bv;

  __shared__ __align__(16) u16 As[128 * 32];
  __shared__ __align__(16) u16 Bs[64 * 32];
  const int tid = threadIdx.x;
  const int wave = tid >> 6;
  const int lane = tid & 63;
  const int quad = lane >> 4;
  const int l16 = lane & 15;
  const int m0 = blockIdx.x * 128;
  const int n0 = blockIdx.y * 64;

  f32x4 acc[2][4];
  #pragma unroll
  for (int i = 0; i < 2; i++)
    #pragma unroll
    for (int j = 0; j < 4; j++) acc[i][j] = (f32x4){0.f, 0.f, 0.f, 0.f};

  if (z == 0 && qfp32) {
    const float* A = XqF;
    const int ar = tid >> 2;
    const int ac = (tid & 3) * 8;

    f32x4 pf[4];
    u16x8 pb;
    {
      pf[0] = *(const f32x4*)(&A[(size_t)(m0 + ar) * GK + ac]);
      pf[1] = *(const f32x4*)(&A[(size_t)(m0 + ar) * GK + ac + 4]);
      pf[2] = *(const f32x4*)(&A[(size_t)(m0 + 64 + ar) * GK + ac]);
      pf[3] = *(const f32x4*)(&A[(size_t)(m0 + 64 + ar) * GK + ac + 4]);
      pb = *(const u16x8*)(&BT[(size_t)(n0 + ar) * GK + ac]);
    }

    for (int kt = 0; kt < 24; kt++) {
      u16x8 h0, h1;
      #pragma unroll
      for (int j = 0; j < 4; j++) {
        h0[j] = f2h(pf[0][j]); h0[4 + j] = f2h(pf[1][j]);
        h1[j] = f2h(pf[2][j]); h1[4 + j] = f2h(pf[3][j]);
      }
      *(u16x8*)(&As[ar * 32 + ac]) = h0;
      *(u16x8*)(&As[(64 + ar) * 32 + ac]) = h1;
      *(u16x8*)(&Bs[ar * 32 + ac]) = pb;
      __syncthreads();

      if (kt + 1 < 24) {
        const int k0 = (kt + 1) * 32;
        pf[0] = *(const f32x4*)(&A[(size_t)(m0 + ar) * GK + k0 + ac]);
        pf[1] = *(const f32x4*)(&A[(size_t)(m0 + ar) * GK + k0 + ac + 4]);
        pf[2] = *(const f32x4*)(&A[(size_t)(m0 + 64 + ar) * GK + k0 + ac]);
        pf[3] = *(const f32x4*)(&A[(size_t)(m0 + 64 + ar) * GK + k0 + ac + 4]);
        pb = *(const u16x8*)(&BT[(size_t)(n0 + ar) * GK + k0 + ac]);
      }

      h16x8 af[2], bf[4];
      #pragma unroll
      for (int mf = 0; mf < 2; mf++)
        af[mf] = *(const h16x8*)(&As[(wave * 32 + mf * 16 + l16) * 32 + quad * 8]);
      #pragma unroll
      for (int nf = 0; nf < 4; nf++)
        bf[nf] = *(const h16x8*)(&Bs[(nf * 16 + l16) * 32 + quad * 8]);
      #pragma unroll
      for (int mf = 0; mf < 2; mf++)
        #pragma unroll
        for (int nf = 0; nf < 4; nf++)
          acc[mf][nf] = __builtin_amdgcn_mfma_f32_16x16x32_f16(af[mf], bf[nf], acc[mf][nf], 0, 0, 0);

      if (kt + 1 < 24) __syncthreads();
    }
  } else {
    const u16* A = (z == 0) ? Xq16 : (z == 1) ? Xk16 : Xv16;
    const int Lr = lane >> 2, Lc = (lane & 3) * 8;
    const u16* gA0 = A + (size_t)(m0 + wave * 32 + Lr) * GK + Lc;
    const u16* gA1 = gA0 + (size_t)16 * GK;
    const u16* gB  = BT + (size_t)(n0 + wave * 16 + Lr) * GK + Lc;
    u16* lA0 = &As[(wave * 32) * 32];
    u16* lA1 = &As[(wave * 32 + 16) * 32];
    u16* lB  = &Bs[(wave * 16) * 32];

    for (int kt = 0; kt < 24; kt++) {
      gll16(gA0, lA0);
      gll16(gA1, lA1);
      gll16(gB, lB);
      gA0 += 32; gA1 += 32; gB += 32;
      __syncthreads();

      h16x8 af[2], bf[4];
      #pragma unroll
      for (int mf = 0; mf < 2; mf++)
        af[mf] = *(const h16x8*)(&As[(wave * 32 + mf * 16 + l16) * 32 + quad * 8]);
      #pragma unroll
      for (int nf = 0; nf < 4; nf++)
        bf[nf] = *(const h16x8*)(&Bs[(nf * 16 + l16) * 32 + quad * 8]);
      #pragma unroll
      for (int mf = 0; mf < 2; mf++)
        #pragma unroll
        for (int nf = 0; nf < 4; nf++)
          acc[mf][nf] = __builtin_amdgcn_mfma_f32_16x16x32_f16(af[mf], bf[nf], acc[mf][nf], 0, 0, 0);
      __syncthreads();
    }
  }

  u16* Yr = (z == 0) ? Q16 : K16;
  #pragma unroll
  for (int nf = 0; nf < 4; nf++) {
    const int n = n0 + nf * 16 + l16;
    const float bv2 = bias[n];
    #pragma unroll
    for (int mf = 0; mf < 2; mf++) {
      const int m = m0 + wave * 32 + mf * 16 + quad * 4;
      if (z == 2) {
        const int b = m >> 11, s = m & 2047;
        u16x4 pk;
        #pragma unroll
        for (int r = 0; r < 4; r++) pk[r] = f2h(acc[mf][nf][r] + bv2);
        *(u16x4*)(&VT[(size_t)b * 768 * 2048 + (size_t)n * 2048 + s]) = pk;
      } else {
        #pragma unroll
        for (int r = 0; r < 4; r++)
          Yr[(size_t)(m + r) * GK + n] = f2h(acc[mf][nf][r] + bv2);
      }
    }
  }
}

// ---------------------------------------------------------------------------
// GEMM_O: out[8192][768] fp32 = A16[8192][768] f16 @ WoT + bo.
// ---------------------------------------------------------------------------
__global__ __launch_bounds__(256) void gemm_o(
    const u16* __restrict__ A, const u16* __restrict__ BT,
    const float* __restrict__ bias, float* __restrict__ Y)
{
  __shared__ __align__(16) u16 As[128 * 32];
  __shared__ __align__(16) u16 Bs[64 * 32];
  const int tid = threadIdx.x;
  const int wave = tid >> 6;
  const int lane = tid & 63;
  const int quad = lane >> 4;
  const int l16 = lane & 15;
  const int m0 = blockIdx.x * 128;
  const int n0 = blockIdx.y * 64;

  f32x4 acc[2][4];
  #pragma unroll
  for (int i = 0; i < 2; i++)
    #pragma unroll
    for (int j = 0; j < 4; j++) acc[i][j] = (f32x4){0.f, 0.f, 0.f, 0.f};

  const int Lr = lane >> 2, Lc = (lane & 3) * 8;
  const u16* gA0 = A + (size_t)(m0 + wave * 32 + Lr) * GK + Lc;
  const u16* gA1 = gA0 + (size_t)16 * GK;
  const u16* gB  = BT + (size_t)(n0 + wave * 16 + Lr) * GK + Lc;
  u16* lA0 = &As[(wave * 32) * 32];
  u16* lA1 = &As[(wave * 32 + 16) * 32];
  u16* lB  = &Bs[(wave * 16) * 32];

  for (int kt = 0; kt < 24; kt++) {
    gll16(gA0, lA0);
    gll16(gA1, lA1);
    gll16(gB, lB);
    gA0 += 32; gA1 += 32; gB += 32;
    __syncthreads();

    h16x8 af[2], bf[4];
    #pragma unroll
    for (int mf = 0; mf < 2; mf++)
      af[mf] = *(const h16x8*)(&As[(wave * 32 + mf * 16 + l16) * 32 + quad * 8]);
    #pragma unroll
    for (int nf = 0; nf < 4; nf++)
      bf[nf] = *(const h16x8*)(&Bs[(nf * 16 + l16) * 32 + quad * 8]);
    #pragma unroll
    for (int mf = 0; mf < 2; mf++)
      #pragma unroll
      for (int nf = 0; nf < 4; nf++)
        acc[mf][nf] = __builtin_amdgcn_mfma_f32_16x16x32_f16(af[mf], bf[nf], acc[mf][nf], 0, 0, 0);
    __syncthreads();
  }

  #pragma unroll
  for (int nf = 0; nf < 4; nf++) {
    const int n = n0 + nf * 16 + l16;
    const float bv = bias[n];
    #pragma unroll
    for (int mf = 0; mf < 2; mf++) {
      const int m = m0 + wave * 32 + mf * 16 + quad * 4;
      #pragma unroll
      for (int r = 0; r < 4; r++)
        Y[(size_t)(m + r) * GK + n] = acc[mf][nf][r] + bv;
    }
  }
}

#define SEQ 2048
#define LQK 104
#define LVT 72
#define LPS 72

// ---------------------------------------------------------------------------
// attn_split: KV-split flash attention. 512 thr / 8 waves x 32 q-rows
// (block = 256 q-rows), grid (8, 32, 2). Each z handles 16 of 32 KV tiles,
// writes normalized f32 partial O + (m_raw, l) per row. LDS 64.0 KB ->
// 2 blocks/CU -> 16 waves/CU with the 32q/wave low-traffic body.
// ---------------------------------------------------------------------------
__global__ __launch_bounds__(512, 4) void attn_split(
    const u16* __restrict__ Q, const u16* __restrict__ K,
    const u16* __restrict__ VT,
    float* __restrict__ Op0, float* __restrict__ Op1, float* __restrict__ ML)
{
  __shared__ __align__(16) u16 Ks[64 * LQK];
  __shared__ __align__(16) u16 Vt[96 * LVT];
  __shared__ __align__(16) u16 Ps[8][32 * LPS];

  const int tid = threadIdx.x;
  const int wave = tid >> 6;
  const int lane = tid & 63;
  const int quad = lane >> 4;
  const int l16 = lane & 15;

  const int bh = blockIdx.y;
  const int b = bh >> 3, h = bh & 7;
  const int q0 = blockIdx.x * 256;
  const int z = blockIdx.z;
  const int kt0 = z * 16, kt1 = kt0 + 16;

  const size_t batch_off = (size_t)b * SEQ * 768;
  const u16* Kg = K + batch_off + h * 96;
  const u16* Vg = VT + (size_t)b * 768 * 2048 + (size_t)(h * 96) * 2048;

  h16x8 qf[2][3];
  #pragma unroll
  for (int mf = 0; mf < 2; mf++) {
    const u16* Qrow = Q + batch_off +
        (size_t)(q0 + wave * 32 + mf * 16 + l16) * 768 + h * 96 + quad * 8;
    #pragma unroll
    for (int ks = 0; ks < 3; ks++) qf[mf][ks] = *(const h16x8*)(&Qrow[ks * 32]);
  }

  // staging: K 64x96 (768 chunks), V 96x64 (768 chunks); chunk tid for all,
  // chunk tid+512 for tid<256 (R1 pattern)
  const int kr0 = tid / 12, kc0 = (tid % 12) * 8;
  const int kr1 = (tid + 512) / 12, kc1 = ((tid + 512) % 12) * 8;
  const int vr0 = tid >> 3, vc0 = (tid & 7) * 8;
  const int vr1 = (tid + 512) >> 3, vc1 = ((tid + 512) & 7) * 8;
  const bool extra = tid < 256;

  f32x4 o[2][6];
  #pragma unroll
  for (int mf = 0; mf < 2; mf++)
    #pragma unroll
    for (int i = 0; i < 6; i++) o[mf][i] = (f32x4){0.f, 0.f, 0.f, 0.f};
  float m_raw[2] = {-1e30f, -1e30f};
  float lrow[2] = {0.f, 0.f};
  const float sc = 0.14724498f;  // log2(e)/sqrt(96)

  u16* Pw = &Ps[wave][0];

  u16x8 kA, kB, vA, vB;
  {
    const u16* K0 = Kg + (size_t)kt0 * 64 * 768;
    const u16* V0 = Vg + (size_t)kt0 * 64;
    kA = *(const u16x8*)(&K0[(size_t)kr0 * 768 + kc0]);
    vA = *(const u16x8*)(&V0[(size_t)vr0 * 2048 + vc0]);
    if (extra) {
      kB = *(const u16x8*)(&K0[(size_t)kr1 * 768 + kc1]);
      vB = *(const u16x8*)(&V0[(size_t)vr1 * 2048 + vc1]);
    }
  }

  for (int kt = kt0; kt < kt1; kt++) {
    *(u16x8*)(&Ks[kr0 * LQK + kc0]) = kA;
    *(u16x8*)(&Vt[vr0 * LVT + vc0]) = vA;
    if (extra) {
      *(u16x8*)(&Ks[kr1 * LQK + kc1]) = kB;
      *(u16x8*)(&Vt[vr1 * LVT + vc1]) = vB;
    }
    __syncthreads();

    if (kt + 1 < kt1) {
      const u16* Kn = Kg + (size_t)(kt + 1) * 64 * 768;
      const u16* Vn = Vg + (size_t)(kt + 1) * 64;
      kA = *(const u16x8*)(&Kn[(size_t)kr0 * 768 + kc0]);
      vA = *(const u16x8*)(&Vn[(size_t)vr0 * 2048 + vc0]);
      if (extra) {
        kB = *(const u16x8*)(&Kn[(size_t)kr1 * 768 + kc1]);
        vB = *(const u16x8*)(&Vn[(size_t)vr1 * 2048 + vc1]);
      }
    }

    // QK^T: K-fragment read once, feeds both mf groups
    f32x4 s[2][4];
    #pragma unroll
    for (int mf = 0; mf < 2; mf++)
      #pragma unroll
      for (int kf = 0; kf < 4; kf++) s[mf][kf] = (f32x4){0.f, 0.f, 0.f, 0.f};
    __builtin_amdgcn_s_setprio(1);
    #pragma unroll
    for (int ks = 0; ks < 3; ks++) {
      #pragma unroll
      for (int kf = 0; kf < 4; kf++) {
        h16x8 a = *(const h16x8*)(&Ks[(kf * 16 + l16) * LQK + ks * 32 + quad * 8]);
        s[0][kf] = __builtin_amdgcn_mfma_f32_16x16x32_f16(a, qf[0][ks], s[0][kf], 0, 0, 0);
        s[1][kf] = __builtin_amdgcn_mfma_f32_16x16x32_f16(a, qf[1][ks], s[1][kf], 0, 0, 0);
      }
    }
    __builtin_amdgcn_s_setprio(0);

    #pragma unroll
    for (int mf = 0; mf < 2; mf++) {
      float mx = s[mf][0][0];
      #pragma unroll
      for (int kf = 0; kf < 4; kf++)
        #pragma unroll
        for (int r = 0; r < 4; r++) mx = fmaxf(mx, s[mf][kf][r]);
      mx = fmaxf(mx, __shfl_xor(mx, 16));
      mx = fmaxf(mx, __shfl_xor(mx, 32));
      // defer-max (T13): P bounded by 2^7.95, f16-safe; cancels in weights.
      if (__any(mx > m_raw[mf] + 54.0f)) {
        const float mnew = fmaxf(m_raw[mf], mx);
        const float alpha = exp2f(sc * (m_raw[mf] - mnew));
        lrow[mf] *= alpha;
        #pragma unroll
        for (int nfo = 0; nfo < 6; nfo++)
          #pragma unroll
          for (int r = 0; r < 4; r++) o[mf][nfo][r] *= alpha;
        m_raw[mf] = mnew;
      }
      const float c0 = sc * m_raw[mf];
      float ps = 0.f;
      #pragma unroll
      for (int kf = 0; kf < 4; kf++)
        #pragma unroll
        for (int r = 0; r < 4; r++) {
          float p = exp2f(fmaf(s[mf][kf][r], sc, -c0));
          s[mf][kf][r] = p;
          ps += p;
        }
      lrow[mf] += ps;

      #pragma unroll
      for (int kf = 0; kf < 4; kf++) {
        fp16x2 a = __builtin_amdgcn_cvt_pkrtz(s[mf][kf][0], s[mf][kf][1]);
        fp16x2 b2 = __builtin_amdgcn_cvt_pkrtz(s[mf][kf][2], s[mf][kf][3]);
        fp16x4 w4; w4[0] = a[0]; w4[1] = a[1]; w4[2] = b2[0]; w4[3] = b2[1];
        *(fp16x4*)(&Pw[(mf * 16 + l16) * LPS + kf * 16 + quad * 4]) = w4;
      }
    }

    // PV: V fragment read once, feeds both mf groups
    __builtin_amdgcn_s_setprio(1);
    #pragma unroll
    for (int ks = 0; ks < 2; ks++) {
      h16x8 pf0 = *(const h16x8*)(&Pw[l16 * LPS + ks * 32 + quad * 8]);
      h16x8 pf1 = *(const h16x8*)(&Pw[(16 + l16) * LPS + ks * 32 + quad * 8]);
      #pragma unroll
      for (int nfo = 0; nfo < 6; nfo++) {
        h16x8 vfr = *(const h16x8*)(&Vt[(nfo * 16 + l16) * LVT + ks * 32 + quad * 8]);
        o[0][nfo] = __builtin_amdgcn_mfma_f32_16x16x32_f16(vfr, pf0, o[0][nfo], 0, 0, 0);
        o[1][nfo] = __builtin_amdgcn_mfma_f32_16x16x32_f16(vfr, pf1, o[1][nfo], 0, 0, 0);
      }
    }
    __builtin_amdgcn_s_setprio(0);
    __syncthreads();
  }

  float* Op = (z == 0) ? Op0 : Op1;
  #pragma unroll
  for (int mf = 0; mf < 2; mf++) {
    float l = lrow[mf];
    l += __shfl_xor(l, 16);
    l += __shfl_xor(l, 32);
    const float inv = 1.0f / l;
    const int row = q0 + wave * 32 + mf * 16 + l16;
    float* Ob = Op + ((size_t)b * SEQ + row) * 768 + h * 96;
    #pragma unroll
    for (int nfo = 0; nfo < 6; nfo++) {
      f32x4 w;
      #pragma unroll
      for (int r = 0; r < 4; r++) w[r] = o[mf][nfo][r] * inv;
      *(f32x4*)(&Ob[nfo * 16 + quad * 4]) = w;
    }
    if (quad == 0) {
      float* mlp = ML + (((size_t)z * 32 + bh) * SEQ + row) * 2;
      mlp[0] = m_raw[mf];
      mlp[1] = l;
    }
  }
}

// ---------------------------------------------------------------------------
// combine: O = (e0*O0 + e1*O1)/(e0+e1), e_i = l_i * 2^(sc*(m_i - mmax)).
// 786432 threads, 8 cols each (within one head). Writes f16 A16.
// ---------------------------------------------------------------------------
__global__ __launch_bounds__(256) void combine_kernel(
    const float* __restrict__ Op0, const float* __restrict__ Op1,
    const float* __restrict__ ML, u16* __restrict__ A16)
{
  const int idx = blockIdx.x * 256 + threadIdx.x;  // 0..786431
  const int row = idx / 96;                        // b*2048 + s
  const int c8 = (idx % 96) * 8;                   // 0..760
  const int h = c8 / 96 + ((c8 % 96) ? 0 : 0);     // head of this 8-col chunk
  const int hh = c8 / 96;
  const int b = row >> 11, s = row & 2047;
  const int bh = b * 8 + hh;
  (void)h;

  const float sc = 0.14724498f;
  const float* ml0 = ML + (((size_t)0 * 32 + bh) * SEQ + s) * 2;
  const float* ml1 = ML + (((size_t)1 * 32 + bh) * SEQ + s) * 2;
  const float m0 = ml0[0], l0 = ml0[1];
  const float m1 = ml1[0], l1 = ml1[1];
  const float mmax = fmaxf(m0, m1);
  const float e0 = l0 * exp2f(sc * (m0 - mmax));
  const float e1 = l1 * exp2f(sc * (m1 - mmax));
  const float inv = 1.0f / (e0 + e1);
  const float w0 = e0 * inv, w1 = e1 * inv;

  const size_t off = (size_t)row * 768 + c8;
  f32x4 a0 = *(const f32x4*)(&Op0[off]);
  f32x4 a1 = *(const f32x4*)(&Op0[off + 4]);
  f32x4 b0 = *(const f32x4*)(&Op1[off]);
  f32x4 b1 = *(const f32x4*)(&Op1[off + 4]);
  u16x8 out;
  #pragma unroll
  for (int r = 0; r < 4; r++) {
    out[r]     = f2h(w0 * a0[r] + w1 * b0[r]);
    out[4 + r] = f2h(w0 * a1[r] + w1 * b1[r]);
  }
  *(u16x8*)(&A16[off]) = out;
}

// ---------------------------------------------------------------------------
// attn_r1: exact R1 single-pass fallback (512thr, 8 waves x 16 q-rows).
// ---------------------------------------------------------------------------
__global__ __launch_bounds__(512, 4) void attn_r1(
    const u16* __restrict__ Q, const u16* __restrict__ K,
    const u16* __restrict__ VT, u16* __restrict__ O)
{
  __shared__ __align__(16) u16 Ks[64 * LQK];
  __shared__ __align__(16) u16 Vt[96 * LVT];
  __shared__ __align__(16) u16 Ps[8][16 * LPS];

  const int tid = threadIdx.x;
  const int wave = tid >> 6;
  const int lane = tid & 63;
  const int quad = lane >> 4;
  const int l16 = lane & 15;

  const int bh = blockIdx.y;
  const int b = bh >> 3, h = bh & 7;
  const int q0 = blockIdx.x * 128;

  const size_t batch_off = (size_t)b * SEQ * 768;
  const u16* Kg = K + batch_off + h * 96;
  const u16* Vg = VT + (size_t)b * 768 * 2048 + (size_t)(h * 96) * 2048;

  h16x8 qf[3];
  {
    const u16* Qrow = Q + batch_off + (size_t)(q0 + wave * 16 + l16) * 768 + h * 96 + quad * 8;
    #pragma unroll
    for (int ks = 0; ks < 3; ks++) qf[ks] = *(const h16x8*)(&Qrow[ks * 32]);
  }

  const int kr0 = tid / 12, kc0 = (tid % 12) * 8;
  const int kr1 = (tid + 512) / 12, kc1 = ((tid + 512) % 12) * 8;
  const int vr0 = tid >> 3, vc0 = (tid & 7) * 8;
  const int vr1 = (tid + 512) >> 3, vc1 = ((tid + 512) & 7) * 8;
  const bool extra = tid < 256;

  f32x4 o[6];
  #pragma unroll
  for (int i = 0; i < 6; i++) o[i] = (f32x4){0.f, 0.f, 0.f, 0.f};
  float m_raw = -1e30f, lrow = 0.f;
  const float sc = 0.14724498f;

  u16* Pw = &Ps[wave][0];

  u16x8 kA, kB, vA, vB;
  kA = *(const u16x8*)(&Kg[(size_t)kr0 * 768 + kc0]);
  vA = *(const u16x8*)(&Vg[(size_t)vr0 * 2048 + vc0]);
  if (extra) {
    kB = *(const u16x8*)(&Kg[(size_t)kr1 * 768 + kc1]);
    vB = *(const u16x8*)(&Vg[(size_t)vr1 * 2048 + vc1]);
  }

  for (int kt = 0; kt < SEQ / 64; kt++) {
    *(u16x8*)(&Ks[kr0 * LQK + kc0]) = kA;
    *(u16x8*)(&Vt[vr0 * LVT + vc0]) = vA;
    if (extra) {
      *(u16x8*)(&Ks[kr1 * LQK + kc1]) = kB;
      *(u16x8*)(&Vt[vr1 * LVT + vc1]) = vB;
    }
    __syncthreads();

    if (kt + 1 < SEQ / 64) {
      const u16* Kn = Kg + (size_t)(kt + 1) * 64 * 768;
      const u16* Vn = Vg + (size_t)(kt + 1) * 64;
      kA = *(const u16x8*)(&Kn[(size_t)kr0 * 768 + kc0]);
      vA = *(const u16x8*)(&Vn[(size_t)vr0 * 2048 + vc0]);
      if (extra) {
        kB = *(const u16x8*)(&Kn[(size_t)kr1 * 768 + kc1]);
        vB = *(const u16x8*)(&Vn[(size_t)vr1 * 2048 + vc1]);
      }
    }

    f32x4 s[4];
    #pragma unroll
    for (int kf = 0; kf < 4; kf++) s[kf] = (f32x4){0.f, 0.f, 0.f, 0.f};
    __builtin_amdgcn_s_setprio(1);
    #pragma unroll
    for (int ks = 0; ks < 3; ks++) {
      #pragma unroll
      for (int kf = 0; kf < 4; kf++) {
        h16x8 a = *(const h16x8*)(&Ks[(kf * 16 + l16) * LQK + ks * 32 + quad * 8]);
        s[kf] = __builtin_amdgcn_mfma_f32_16x16x32_f16(a, qf[ks], s[kf], 0, 0, 0);
      }
    }
    __builtin_amdgcn_s_setprio(0);

    float mx = s[0][0];
    #pragma unroll
    for (int kf = 0; kf < 4; kf++)
      #pragma unroll
      for (int r = 0; r < 4; r++) mx = fmaxf(mx, s[kf][r]);
    mx = fmaxf(mx, __shfl_xor(mx, 16));
    mx = fmaxf(mx, __shfl_xor(mx, 32));
    if (__any(mx > m_raw + 54.0f)) {
      const float mnew = fmaxf(m_raw, mx);
      const float alpha = exp2f(sc * (m_raw - mnew));
      lrow *= alpha;
      #pragma unroll
      for (int nfo = 0; nfo < 6; nfo++)
        #pragma unroll
        for (int r = 0; r < 4; r++) o[nfo][r] *= alpha;
      m_raw = mnew;
    }
    const float c0 = sc * m_raw;
    float ps = 0.f;
    #pragma unroll
    for (int kf = 0; kf < 4; kf++)
      #pragma unroll
      for (int r = 0; r < 4; r++) {
        float p = exp2f(fmaf(s[kf][r], sc, -c0));
        s[kf][r] = p;
        ps += p;
      }
    lrow += ps;

    #pragma unroll
    for (int kf = 0; kf < 4; kf++)
      #pragma unroll
      for (int rp = 0; rp < 4; rp += 2) {
        fp16x2 pk = __builtin_amdgcn_cvt_pkrtz(s[kf][rp], s[kf][rp + 1]);
        *(fp16x2*)(&Pw[l16 * LPS + kf * 16 + quad * 4 + rp]) = pk;
      }

    __builtin_amdgcn_s_setprio(1);
    #pragma unroll
    for (int ks = 0; ks < 2; ks++) {
      h16x8 pfr = *(const h16x8*)(&Pw[l16 * LPS + ks * 32 + quad * 8]);
      #pragma unroll
      for (int nfo = 0; nfo < 6; nfo++) {
        h16x8 vfr = *(const h16x8*)(&Vt[(nfo * 16 + l16) * LVT + ks * 32 + quad * 8]);
        o[nfo] = __builtin_amdgcn_mfma_f32_16x16x32_f16(vfr, pfr, o[nfo], 0, 0, 0);
      }
    }
    __builtin_amdgcn_s_setprio(0);
    __syncthreads();
  }

  lrow += __shfl_xor(lrow, 16);
  lrow += __shfl_xor(lrow, 32);
  const float inv = 1.0f / lrow;
  u16* Ob = O + batch_off + (size_t)(q0 + wave * 16 + l16) * 768 + h * 96;
  #pragma unroll
  for (int nfo = 0; nfo < 6; nfo++) {
    fp16x2 lo = __builtin_amdgcn_cvt_pkrtz(o[nfo][0] * inv, o[nfo][1] * inv);
    fp16x2 hi = __builtin_amdgcn_cvt_pkrtz(o[nfo][2] * inv, o[nfo][3] * inv);
    *(fp16x2*)(&Ob[nfo * 16 + quad * 4]) = lo;
    *(fp16x2*)(&Ob[nfo * 16 + quad * 4 + 2]) = hi;
  }
}

// ---------------------------------------------------------------------------
extern "C" void kernel_launch(void* const* d_in, const int* in_sizes, int n_in,
                              void* d_out, int out_size, void* d_ws, size_t ws_size,
                              hipStream_t stream) {
  const float* Xq = (const float*)d_in[0];
  const float* Xk = (const float*)d_in[1];
  const float* Xv = (const float*)d_in[2];
  const float* Wq = (const float*)d_in[3];
  const float* bq = (const float*)d_in[4];
  const float* Wk = (const float*)d_in[5];
  const float* bk = (const float*)d_in[6];
  const float* Wv = (const float*)d_in[7];
  const float* bv = (const float*)d_in[8];
  const float* Wo = (const float*)d_in[9];
  const float* bo = (const float*)d_in[10];

  u16* wsu = (u16*)d_ws;
  u16* WT   = wsu;                    // 3 x 589824
  u16* WoT  = wsu + 3 * 589824;
  u16* Q16  = wsu + 4 * 589824;       // u16 off 2359296
  u16* Xk16 = Q16 + 6291456;          // u16 off 8650752
  u16* Xv16 = Xk16 + 6291456;         // u16 off 14942208
  u16* Xq16 = Xv16 + 6291456;         // u16 off 21233664; ends 27525120 (55.05MB)

  // f32 partials for KV-split: Op0 overlays Xk16+Xv16 (dead during attn),
  // Op1 at Xq16 (extends 12.58MB past), ML after.
  float* Op0 = (float*)(wsu + 8650752);
  float* Op1 = (float*)(wsu + 21233664);
  float* ML  = (float*)((char*)d_ws + 67633152);

  const size_t need_q16   = (size_t)(4 * 589824 + 4 * 6291456) * 2;  // 55.05MB
  const size_t need_split = 68681728ULL;                             // 68.7MB
  const int q16 = (ws_size >= need_q16) ? 1 : 0;
  const int do_split = (ws_size >= need_split) ? 1 : 0;
  const int nx = q16 ? 3 : 2;

  u16* outu = (u16*)d_out;
  u16* VTb = outu;                   // V^T f16 [4][768][2048]
  u16* K16 = outu + 6291456;         // K f16 rowmajor

  u16* A16 = (u16*)d_in[0];          // attn out (Xq dead after QKV GEMM)

  prep_kernel<<<1152 + 3072 * nx, 256, 0, stream>>>(
      Wq, Wk, Wv, Wo, Xk, Xv, Xq,
      WT, WT + 589824, WT + 2 * 589824, WoT, Xk16, Xv16, Xq16);
  gemm_qkv<<<dim3(64, 12, 3), 256, 0, stream>>>(
      Xq, Xq16, Xk16, Xv16, WT, bq, bk, bv, Q16, K16, VTb, q16 ? 0 : 1);
  if (do_split) {
    attn_split<<<dim3(8, 32, 2), 512, 0, stream>>>(Q16, K16, VTb, Op0, Op1, ML);
    combine_kernel<<<3072, 256, 0, stream>>>(Op0, Op1, ML, A16);
  } else {
    attn_r1<<<dim3(16, 32), 512, 0, stream>>>(Q16, K16, VTb, A16);
  }
  gemm_o<<<dim3(64, 12), 256, 0, stream>>>(A16, WoT, bo, (float*)d_out);
}

// Round 4
// 291.771 us; speedup vs baseline: 1.2762x; 1.2762x over previous
//
#include <hip/hip_runtime.h>

// Multi-head attention, B=4 S=2048 D=768 H=8 DH=96. FP32 I/O, f16 MFMA compute.
// R12: (a) attn reverted to R1 single-pass structure (99us known) + dbuf K/V
//      LDS with ONE barrier/iter and write-late staging + fp16x4 P writes.
//      (b) gemm_qkv/gemm_o tiles 128x64 -> 128x128 (m93 ladder step).
//      (c) prep weight transposes via LDS tiles (coalesced r/w).
// Buffers: ws = [WqT|WkT|WvT|WoT (4.7MB) | Q16 | Xk16 | Xv16 | Xq16] = 55.05MB
//          (harness ws proven >= 68.7MB in R3)
//          d_out = [VT (12.6MB) | K16 (12.6MB)] f16 until GEMM_O overwrites.
//          A16 -> Xq buffer (dead after QKV GEMM; harness restores d_in).

typedef unsigned short u16;
typedef _Float16 h16;
typedef h16 h16x8 __attribute__((ext_vector_type(8)));
typedef __fp16 fp16x2 __attribute__((ext_vector_type(2)));
typedef __fp16 fp16x4 __attribute__((ext_vector_type(4)));
typedef unsigned short u16x8 __attribute__((ext_vector_type(8)));
typedef unsigned short u16x4 __attribute__((ext_vector_type(4)));
typedef float f32x4 __attribute__((ext_vector_type(4)));

__device__ __forceinline__ u16 f2h(float f) {
  union { h16 h; u16 u; } c; c.h = (h16)f; return c.u;
}

__device__ __forceinline__ void gll16(const void* g, void* l) {
  __builtin_amdgcn_global_load_lds(
      (const __attribute__((address_space(1))) void*)g,
      (__attribute__((address_space(3))) void*)l, 16, 0, 0);
}

// ---------------------------------------------------------------------------
// prep: LDS-tiled weight transposes + X f16 conversions.
// Regions by blockIdx.x:
//   [0,288):   WqT/WkT/WvT tiles  (w,h,dt): T[h*96+kk][d] from W[h][d][kk]
//   [288,432): WoT tiles (kt,nt): WoT[n][k] from Wo[k][n]
//   [432,9648): X cvt: 3 tensors x 3072 blocks, u16x8 per thread
// ---------------------------------------------------------------------------
__global__ __launch_bounds__(256) void prep_kernel(
    const float* __restrict__ Wq, const float* __restrict__ Wk,
    const float* __restrict__ Wv, const float* __restrict__ Wo,
    const float* __restrict__ Xk, const float* __restrict__ Xv,
    const float* __restrict__ Xq,
    u16* __restrict__ WqT, u16* __restrict__ WkT,
    u16* __restrict__ WvT, u16* __restrict__ WoT,
    u16* __restrict__ Xk16, u16* __restrict__ Xv16, u16* __restrict__ Xq16)
{
  const int bid = blockIdx.x;
  const int tid = threadIdx.x;

  if (bid >= 432) {
    // ---- X cvt ----
    const int i = bid - 432;
    const int t = i / 3072;                       // 0: Xk  1: Xv  2: Xq
    const long e = ((long)(i % 3072) * 256 + tid) * 8;
    const float* src = (t == 0) ? Xk : (t == 1) ? Xv : Xq;
    u16* dst = (t == 0) ? Xk16 : (t == 1) ? Xv16 : Xq16;
    f32x4 a = *(const f32x4*)(&src[e]);
    f32x4 b = *(const f32x4*)(&src[e + 4]);
    u16x8 v;
    #pragma unroll
    for (int j = 0; j < 4; j++) { v[j] = f2h(a[j]); v[4 + j] = f2h(b[j]); }
    *(u16x8*)(&dst[e]) = v;
    return;
  }

  if (bid < 288) {
    // ---- Wq/Wk/Wv transpose tile ----
    __shared__ u16 Lt[96][72];                    // [kk][d-in-tile], pad 72
    const int w = bid / 96;                       // weight
    const int r = bid % 96;
    const int h = r / 12, dt = r % 12;            // head, d-tile (64 d)
    const float* W = (w == 0) ? Wq : (w == 1) ? Wk : Wv;
    u16* T = (w == 0) ? WqT : (w == 1) ? WkT : WvT;
    const float* src = W + (size_t)h * 73728 + (size_t)dt * 64 * 96;  // [64][96]
    #pragma unroll
    for (int p = 0; p < 6; p++) {
      const int lin = p * 1024 + tid * 4;         // 0..6143
      f32x4 v = *(const f32x4*)(&src[lin]);
      const int d = lin / 96, kk = lin % 96;      // 4 elems same d (96%4==0)
      #pragma unroll
      for (int j = 0; j < 4; j++) Lt[kk + j][d] = f2h(v[j]);
    }
    __syncthreads();
    #pragma unroll
    for (int c = 0; c < 3; c++) {
      const int ch = c * 256 + tid;               // 0..767
      const int kk = ch >> 3, dc = ch & 7;
      u16x8 o = *(const u16x8*)(&Lt[kk][dc * 8]);
      *(u16x8*)(&T[(size_t)(h * 96 + kk) * 768 + dt * 64 + dc * 8]) = o;
    }
    return;
  }

  // ---- Wo transpose tile (64x64) ----
  {
    __shared__ u16 Lo[64][72];                    // [n][k], pad 72
    const int i = bid - 288;
    const int kt = i / 12, nt = i % 12;
    const float* src = Wo + (size_t)(kt * 64) * 768 + nt * 64;
    #pragma unroll
    for (int p = 0; p < 4; p++) {
      const int lin = p * 1024 + tid * 4;         // 0..4095
      const int kr = lin >> 6, nc = lin & 63;
      f32x4 v = *(const f32x4*)(&src[(size_t)kr * 768 + nc]);
      #pragma unroll
      for (int j = 0; j < 4; j++) Lo[nc + j][kr] = f2h(v[j]);
    }
    __syncthreads();
    #pragma unroll
    for (int c = 0; c < 2; c++) {
      const int ch = c * 256 + tid;               // 0..511
      const int nr = ch >> 3, kc = ch & 7;
      u16x8 o = *(const u16x8*)(&Lo[nr][kc * 8]);
      *(u16x8*)(&WoT[(size_t)(nt * 64 + nr) * 768 + kt * 64 + kc * 8]) = o;
    }
  }
}

// ---------------------------------------------------------------------------
// Batched QKV GEMM, BM=128 BN=128 BK=32, gll16 staging (A all f16).
// grid (64, 6, 3). 256 thr / 4 waves; wave owns 32 m-rows x 128 n.
// ---------------------------------------------------------------------------
#define GK 768

__global__ __launch_bounds__(256) void gemm_qkv(
    const u16* __restrict__ Xq16, const u16* __restrict__ Xk16,
    const u16* __restrict__ Xv16, const u16* __restrict__ WT,
    const float* __restrict__ bq, const float* __restrict__ bk,
    const float* __restrict__ bv,
    u16* __restrict__ Q16, u16* __restrict__ K16, u16* __restrict__ VT)
{
  const int z = blockIdx.z;
  const u16* BT = WT + (size_t)z * 589824;
  const float* bias = (z == 0) ? bq : (z == 1) ? bk : bv;
  const u16* A = (z == 0) ? Xq16 : (z == 1) ? Xk16 : Xv16;

  __shared__ __align__(16) u16 As[128 * 32];
  __shared__ __align__(16) u16 Bs[128 * 32];
  const int tid = threadIdx.x;
  const int wave = tid >> 6;
  const int lane = tid & 63;
  const int quad = lane >> 4;
  const int l16 = lane & 15;
  const int m0 = blockIdx.x * 128;
  const int n0 = blockIdx.y * 128;

  f32x4 acc[2][8];
  #pragma unroll
  for (int i = 0; i < 2; i++)
    #pragma unroll
    for (int j = 0; j < 8; j++) acc[i][j] = (f32x4){0.f, 0.f, 0.f, 0.f};

  const int Lr = lane >> 2, Lc = (lane & 3) * 8;
  const u16* gA0 = A + (size_t)(m0 + wave * 32 + Lr) * GK + Lc;
  const u16* gA1 = gA0 + (size_t)16 * GK;
  const u16* gB0 = BT + (size_t)(n0 + wave * 32 + Lr) * GK + Lc;
  const u16* gB1 = gB0 + (size_t)16 * GK;
  u16* lA0 = &As[(wave * 32) * 32];
  u16* lA1 = &As[(wave * 32 + 16) * 32];
  u16* lB0 = &Bs[(wave * 32) * 32];
  u16* lB1 = &Bs[(wave * 32 + 16) * 32];

  for (int kt = 0; kt < 24; kt++) {
    gll16(gA0, lA0);
    gll16(gA1, lA1);
    gll16(gB0, lB0);
    gll16(gB1, lB1);
    gA0 += 32; gA1 += 32; gB0 += 32; gB1 += 32;
    __syncthreads();

    h16x8 af[2], bf[8];
    #pragma unroll
    for (int mf = 0; mf < 2; mf++)
      af[mf] = *(const h16x8*)(&As[(wave * 32 + mf * 16 + l16) * 32 + quad * 8]);
    #pragma unroll
    for (int nf = 0; nf < 8; nf++)
      bf[nf] = *(const h16x8*)(&Bs[(nf * 16 + l16) * 32 + quad * 8]);
    #pragma unroll
    for (int mf = 0; mf < 2; mf++)
      #pragma unroll
      for (int nf = 0; nf < 8; nf++)
        acc[mf][nf] = __builtin_amdgcn_mfma_f32_16x16x32_f16(af[mf], bf[nf], acc[mf][nf], 0, 0, 0);
    __syncthreads();
  }

  u16* Yr = (z == 0) ? Q16 : K16;
  #pragma unroll
  for (int nf = 0; nf < 8; nf++) {
    const int n = n0 + nf * 16 + l16;
    const float bv2 = bias[n];
    #pragma unroll
    for (int mf = 0; mf < 2; mf++) {
      const int m = m0 + wave * 32 + mf * 16 + quad * 4;
      if (z == 2) {
        const int b = m >> 11, s = m & 2047;
        u16x4 pk;
        #pragma unroll
        for (int r = 0; r < 4; r++) pk[r] = f2h(acc[mf][nf][r] + bv2);
        *(u16x4*)(&VT[(size_t)b * 768 * 2048 + (size_t)n * 2048 + s]) = pk;
      } else {
        #pragma unroll
        for (int r = 0; r < 4; r++)
          Yr[(size_t)(m + r) * GK + n] = f2h(acc[mf][nf][r] + bv2);
      }
    }
  }
}

// ---------------------------------------------------------------------------
// GEMM_O: out[8192][768] fp32 = A16 f16 @ WoT + bo. BM=128 BN=128. grid (64,6).
// ---------------------------------------------------------------------------
__global__ __launch_bounds__(256) void gemm_o(
    const u16* __restrict__ A, const u16* __restrict__ BT,
    const float* __restrict__ bias, float* __restrict__ Y)
{
  __shared__ __align__(16) u16 As[128 * 32];
  __shared__ __align__(16) u16 Bs[128 * 32];
  const int tid = threadIdx.x;
  const int wave = tid >> 6;
  const int lane = tid & 63;
  const int quad = lane >> 4;
  const int l16 = lane & 15;
  const int m0 = blockIdx.x * 128;
  const int n0 = blockIdx.y * 128;

  f32x4 acc[2][8];
  #pragma unroll
  for (int i = 0; i < 2; i++)
    #pragma unroll
    for (int j = 0; j < 8; j++) acc[i][j] = (f32x4){0.f, 0.f, 0.f, 0.f};

  const int Lr = lane >> 2, Lc = (lane & 3) * 8;
  const u16* gA0 = A + (size_t)(m0 + wave * 32 + Lr) * GK + Lc;
  const u16* gA1 = gA0 + (size_t)16 * GK;
  const u16* gB0 = BT + (size_t)(n0 + wave * 32 + Lr) * GK + Lc;
  const u16* gB1 = gB0 + (size_t)16 * GK;
  u16* lA0 = &As[(wave * 32) * 32];
  u16* lA1 = &As[(wave * 32 + 16) * 32];
  u16* lB0 = &Bs[(wave * 32) * 32];
  u16* lB1 = &Bs[(wave * 32 + 16) * 32];

  for (int kt = 0; kt < 24; kt++) {
    gll16(gA0, lA0);
    gll16(gA1, lA1);
    gll16(gB0, lB0);
    gll16(gB1, lB1);
    gA0 += 32; gA1 += 32; gB0 += 32; gB1 += 32;
    __syncthreads();

    h16x8 af[2], bf[8];
    #pragma unroll
    for (int mf = 0; mf < 2; mf++)
      af[mf] = *(const h16x8*)(&As[(wave * 32 + mf * 16 + l16) * 32 + quad * 8]);
    #pragma unroll
    for (int nf = 0; nf < 8; nf++)
      bf[nf] = *(const h16x8*)(&Bs[(nf * 16 + l16) * 32 + quad * 8]);
    #pragma unroll
    for (int mf = 0; mf < 2; mf++)
      #pragma unroll
      for (int nf = 0; nf < 8; nf++)
        acc[mf][nf] = __builtin_amdgcn_mfma_f32_16x16x32_f16(af[mf], bf[nf], acc[mf][nf], 0, 0, 0);
    __syncthreads();
  }

  #pragma unroll
  for (int nf = 0; nf < 8; nf++) {
    const int n = n0 + nf * 16 + l16;
    const float bv = bias[n];
    #pragma unroll
    for (int mf = 0; mf < 2; mf++) {
      const int m = m0 + wave * 32 + mf * 16 + quad * 4;
      #pragma unroll
      for (int r = 0; r < 4; r++)
        Y[(size_t)(m + r) * GK + n] = acc[mf][nf][r] + bv;
    }
  }
}

// ---------------------------------------------------------------------------
// Flash attention (R1 structure + dbuf K/V, one barrier/iter, write-late).
// Q,K: [4][2048][768] f16; VT: [4][768][2048] f16. 512 thr / 8 waves,
// 128 q-rows/block (16 per wave); grid (16,32). LDS 72.7KB -> 2 blocks/CU.
// defer-max (T13, THR raw=54); setprio around MFMA (T5).
// ---------------------------------------------------------------------------
#define SEQ 2048
#define NT 32
#define LQK 104
#define LVT 72
#define LPS 72

__global__ __launch_bounds__(512, 4) void attn_kernel(
    const u16* __restrict__ Q, const u16* __restrict__ K,
    const u16* __restrict__ VT, u16* __restrict__ O)
{
  __shared__ __align__(16) u16 Ks[2][64 * LQK];
  __shared__ __align__(16) u16 Vt[2][96 * LVT];
  __shared__ __align__(16) u16 Ps[8][16 * LPS];

  const int tid = threadIdx.x;
  const int wave = tid >> 6;
  const int lane = tid & 63;
  const int quad = lane >> 4;
  const int l16 = lane & 15;

  const int bh = blockIdx.y;
  const int b = bh >> 3, h = bh & 7;
  const int q0 = blockIdx.x * 128;

  const size_t batch_off = (size_t)b * SEQ * 768;
  const u16* Kg = K + batch_off + h * 96;
  const u16* Vg = VT + (size_t)b * 768 * 2048 + (size_t)(h * 96) * 2048;

  h16x8 qf[3];
  {
    const u16* Qrow = Q + batch_off + (size_t)(q0 + wave * 16 + l16) * 768 + h * 96 + quad * 8;
    #pragma unroll
    for (int ks = 0; ks < 3; ks++) qf[ks] = *(const h16x8*)(&Qrow[ks * 32]);
  }

  const int kr0 = tid / 12, kc0 = (tid % 12) * 8;
  const int kr1 = (tid + 512) / 12, kc1 = ((tid + 512) % 12) * 8;
  const int vr0 = tid >> 3, vc0 = (tid & 7) * 8;
  const int vr1 = (tid + 512) >> 3, vc1 = ((tid + 512) & 7) * 8;
  const bool extra = tid < 256;

  f32x4 o[6];
  #pragma unroll
  for (int i = 0; i < 6; i++) o[i] = (f32x4){0.f, 0.f, 0.f, 0.f};
  float m_raw = -1e30f, lrow = 0.f;   // lrow: this lane's quad-partial
  const float sc = 0.14724498f;       // log2(e)/sqrt(96)

  u16* Pw = &Ps[wave][0];

  u16x8 kA, kB, vA, vB;
  // ---- prolog: stage tile 0, then load tile 1 into regs ----
  kA = *(const u16x8*)(&Kg[(size_t)kr0 * 768 + kc0]);
  vA = *(const u16x8*)(&Vg[(size_t)vr0 * 2048 + vc0]);
  if (extra) {
    kB = *(const u16x8*)(&Kg[(size_t)kr1 * 768 + kc1]);
    vB = *(const u16x8*)(&Vg[(size_t)vr1 * 2048 + vc1]);
  }
  *(u16x8*)(&Ks[0][kr0 * LQK + kc0]) = kA;
  *(u16x8*)(&Vt[0][vr0 * LVT + vc0]) = vA;
  if (extra) {
    *(u16x8*)(&Ks[0][kr1 * LQK + kc1]) = kB;
    *(u16x8*)(&Vt[0][vr1 * LVT + vc1]) = vB;
  }
  {
    const u16* Kn = Kg + (size_t)64 * 768;
    const u16* Vn = Vg + 64;
    kA = *(const u16x8*)(&Kn[(size_t)kr0 * 768 + kc0]);
    vA = *(const u16x8*)(&Vn[(size_t)vr0 * 2048 + vc0]);
    if (extra) {
      kB = *(const u16x8*)(&Kn[(size_t)kr1 * 768 + kc1]);
      vB = *(const u16x8*)(&Vn[(size_t)vr1 * 2048 + vc1]);
    }
  }
  __syncthreads();

  for (int kt = 0; kt < NT; kt++) {
    const int cur = kt & 1;
    const u16* Kc = &Ks[cur][0];
    const u16* Vc = &Vt[cur][0];

    // QK^T
    f32x4 s[4];
    #pragma unroll
    for (int kf = 0; kf < 4; kf++) s[kf] = (f32x4){0.f, 0.f, 0.f, 0.f};
    __builtin_amdgcn_s_setprio(1);
    #pragma unroll
    for (int ks = 0; ks < 3; ks++) {
      #pragma unroll
      for (int kf = 0; kf < 4; kf++) {
        h16x8 a = *(const h16x8*)(&Kc[(kf * 16 + l16) * LQK + ks * 32 + quad * 8]);
        s[kf] = __builtin_amdgcn_mfma_f32_16x16x32_f16(a, qf[ks], s[kf], 0, 0, 0);
      }
    }
    __builtin_amdgcn_s_setprio(0);

    // online softmax (defer-max T13)
    float mx = s[0][0];
    #pragma unroll
    for (int kf = 0; kf < 4; kf++)
      #pragma unroll
      for (int r = 0; r < 4; r++) mx = fmaxf(mx, s[kf][r]);
    mx = fmaxf(mx, __shfl_xor(mx, 16));
    mx = fmaxf(mx, __shfl_xor(mx, 32));
    if (__any(mx > m_raw + 54.0f)) {
      const float mnew = fmaxf(m_raw, mx);
      const float alpha = exp2f(sc * (m_raw - mnew));   // 0 on first tile
      lrow *= alpha;
      #pragma unroll
      for (int nfo = 0; nfo < 6; nfo++)
        #pragma unroll
        for (int r = 0; r < 4; r++) o[nfo][r] *= alpha;
      m_raw = mnew;
    }
    const float c0 = sc * m_raw;
    float ps = 0.f;
    #pragma unroll
    for (int kf = 0; kf < 4; kf++)
      #pragma unroll
      for (int r = 0; r < 4; r++) {
        float p = exp2f(fmaf(s[kf][r], sc, -c0));
        s[kf][r] = p;
        ps += p;
      }
    lrow += ps;   // quad-partial; cross-quad combine deferred to epilogue

    // P -> LDS (fp16x4, 4 stores)
    #pragma unroll
    for (int kf = 0; kf < 4; kf++) {
      fp16x2 a2 = __builtin_amdgcn_cvt_pkrtz(s[kf][0], s[kf][1]);
      fp16x2 b2 = __builtin_amdgcn_cvt_pkrtz(s[kf][2], s[kf][3]);
      fp16x4 w4; w4[0] = a2[0]; w4[1] = a2[1]; w4[2] = b2[0]; w4[3] = b2[1];
      *(fp16x4*)(&Pw[l16 * LPS + kf * 16 + quad * 4]) = w4;
    }

    // PV
    __builtin_amdgcn_s_setprio(1);
    #pragma unroll
    for (int ks = 0; ks < 2; ks++) {
      h16x8 pfr = *(const h16x8*)(&Pw[l16 * LPS + ks * 32 + quad * 8]);
      #pragma unroll
      for (int nfo = 0; nfo < 6; nfo++) {
        h16x8 vfr = *(const h16x8*)(&Vc[(nfo * 16 + l16) * LVT + ks * 32 + quad * 8]);
        o[nfo] = __builtin_amdgcn_mfma_f32_16x16x32_f16(vfr, pfr, o[nfo], 0, 0, 0);
      }
    }
    __builtin_amdgcn_s_setprio(0);

    // write-late staging of tile kt+1, then issue loads for kt+2
    if (kt + 1 < NT) {
      u16* Kw = &Ks[cur ^ 1][0];
      u16* Vw = &Vt[cur ^ 1][0];
      *(u16x8*)(&Kw[kr0 * LQK + kc0]) = kA;
      *(u16x8*)(&Vw[vr0 * LVT + vc0]) = vA;
      if (extra) {
        *(u16x8*)(&Kw[kr1 * LQK + kc1]) = kB;
        *(u16x8*)(&Vw[vr1 * LVT + vc1]) = vB;
      }
      if (kt + 2 < NT) {
        const u16* Kn = Kg + (size_t)(kt + 2) * 64 * 768;
        const u16* Vn = Vg + (size_t)(kt + 2) * 64;
        kA = *(const u16x8*)(&Kn[(size_t)kr0 * 768 + kc0]);
        vA = *(const u16x8*)(&Vn[(size_t)vr0 * 2048 + vc0]);
        if (extra) {
          kB = *(const u16x8*)(&Kn[(size_t)kr1 * 768 + kc1]);
          vB = *(const u16x8*)(&Vn[(size_t)vr1 * 2048 + vc1]);
        }
      }
      __syncthreads();
    }
  }

  lrow += __shfl_xor(lrow, 16);
  lrow += __shfl_xor(lrow, 32);
  const float inv = 1.0f / lrow;
  u16* Ob = O + batch_off + (size_t)(q0 + wave * 16 + l16) * 768 + h * 96;
  #pragma unroll
  for (int nfo = 0; nfo < 6; nfo++) {
    fp16x2 lo = __builtin_amdgcn_cvt_pkrtz(o[nfo][0] * inv, o[nfo][1] * inv);
    fp16x2 hi = __builtin_amdgcn_cvt_pkrtz(o[nfo][2] * inv, o[nfo][3] * inv);
    *(fp16x2*)(&Ob[nfo * 16 + quad * 4]) = lo;
    *(fp16x2*)(&Ob[nfo * 16 + quad * 4 + 2]) = hi;
  }
}

// ---------------------------------------------------------------------------
extern "C" void kernel_launch(void* const* d_in, const int* in_sizes, int n_in,
                              void* d_out, int out_size, void* d_ws, size_t ws_size,
                              hipStream_t stream) {
  const float* Xq = (const float*)d_in[0];
  const float* Xk = (const float*)d_in[1];
  const float* Xv = (const float*)d_in[2];
  const float* Wq = (const float*)d_in[3];
  const float* bq = (const float*)d_in[4];
  const float* Wk = (const float*)d_in[5];
  const float* bk = (const float*)d_in[6];
  const float* Wv = (const float*)d_in[7];
  const float* bv = (const float*)d_in[8];
  const float* Wo = (const float*)d_in[9];
  const float* bo = (const float*)d_in[10];

  u16* wsu = (u16*)d_ws;
  u16* WT   = wsu;                    // WqT | WkT | WvT, 589824 each
  u16* WoT  = wsu + 3 * 589824;
  u16* Q16  = wsu + 4 * 589824;       // 12.6 MB
  u16* Xk16 = Q16 + 6291456;          // 12.6 MB
  u16* Xv16 = Xk16 + 6291456;         // 12.6 MB
  u16* Xq16 = Xv16 + 6291456;         // 12.6 MB (total 55.05 MB; ws >= 68.7 proven)

  u16* outu = (u16*)d_out;
  u16* VTb = outu;                   // V^T f16 [4][768][2048]
  u16* K16 = outu + 6291456;         // K f16 rowmajor

  u16* A16 = (u16*)d_in[0];          // attn out (Xq dead after QKV GEMM)

  prep_kernel<<<9648, 256, 0, stream>>>(
      Wq, Wk, Wv, Wo, Xk, Xv, Xq,
      WT, WT + 589824, WT + 2 * 589824, WoT, Xk16, Xv16, Xq16);
  gemm_qkv<<<dim3(64, 6, 3), 256, 0, stream>>>(
      Xq16, Xk16, Xv16, WT, bq, bk, bv, Q16, K16, VTb);
  attn_kernel<<<dim3(16, 32), 512, 0, stream>>>(Q16, K16, VTb, A16);
  gemm_o<<<dim3(64, 6), 256, 0, stream>>>(A16, WoT, bo, (float*)d_out);
}